// Round 8
// baseline (281.284 us; speedup 1.0000x reference)
//
#include <hip/hip_runtime.h>
#include <hip/hip_bf16.h>
#include <math.h>

#define D_IN 256
#define D_OUT 128
#define WSCALE 1073741824.0f   // 2^30 fixed-point scale for edge weights

typedef __bf16 bf16x8 __attribute__((ext_vector_type(8)));
typedef float  f32x4  __attribute__((ext_vector_type(4)));

__device__ __forceinline__ float b2f(ushort u) {
    union { unsigned int i; float f; } v; v.i = ((unsigned int)u) << 16; return v.f;
}
__device__ __forceinline__ ushort f2b(float f) {   // RNE
    unsigned int x = __float_as_uint(f);
    unsigned int r = (x + 0x7FFFu + ((x >> 16) & 1u)) >> 16;
    return (ushort)r;
}

// ---------------------------------------------------------------- W^T precompute (fp32 -> bf16)
__global__ void wt_k(const float* __restrict__ W, ushort* __restrict__ Wtg) {
    int t = blockIdx.x * 256 + threadIdx.x;   // 256*128 = 32768
    if (t < D_IN * D_OUT) {
        int k = t >> 7, n = t & 127;
        Wtg[n * D_IN + k] = f2b(W[t]);
    }
}

// ---------------------------------------------------------------- fused: edge atomics || MFMA GEMM
// GEMM blocks interleaved 1-in-5 so MFMA work is co-resident with the
// latency-bound edge-atomic blocks for the whole dispatch.
__global__ __launch_bounds__(256, 4) void fused_k(const int* __restrict__ dst,
                                                  const float* __restrict__ w,
                                                  unsigned long long* __restrict__ packed,
                                                  int* __restrict__ pos, int E, int GB,
                                                  const float* __restrict__ X,
                                                  const ushort* __restrict__ Wtg,
                                                  ushort* __restrict__ H, int M) {
    const unsigned b = blockIdx.x;
    const int g5 = b / 5;
    const bool isg = (b % 5 == 0) && (g5 < GB);
    if (!isg) {
        int ng = g5 + ((b % 5) ? 1 : 0);
        if (ng > GB) ng = GB;
        int e = (b - ng) * 256 + threadIdx.x;
        if (e < E) {
            int d = dst[e];
            unsigned long long inc = (1ull << 40) |
                (unsigned long long)(w[e] * WSCALE);
            unsigned long long old = atomicAdd(&packed[d], inc);
            pos[e] = (int)(old >> 40);
        }
        return;
    }
    // ------------- GEMM path: BM=64 rows/block, 4 waves, each wave 64 rows x 32 cols
    extern __shared__ char smem[];            // 32768 B = xs[64 rows][256 bf16] swizzled
    const int t = threadIdx.x;
    const int brow = g5 * 64;
    const int wid = t >> 6;
    const int lane = t & 63;
    const int lrow = lane & 15;
    const int lkc = lane >> 4;                // 0..3

    // preload B fragments: cols wid*32 + n*16 + lrow, k = kk*32 + lkc*8
    bf16x8 breg[2][8];
    #pragma unroll
    for (int n = 0; n < 2; ++n) {
        int col = wid * 32 + n * 16 + lrow;
        const char* base = (const char*)(Wtg + col * D_IN);
        #pragma unroll
        for (int kk = 0; kk < 8; ++kk)
            breg[n][kk] = *(const bf16x8*)(base + kk * 64 + lkc * 16);
    }

    // stage x tile: 64 rows x 256 fp32 -> bf16 LDS (16B-chunk XOR swizzle)
    {
        const float4* x4 = (const float4*)X;
        #pragma unroll
        for (int i = 0; i < 16; ++i) {
            int f = t + 256 * i;              // 4096 float4s
            int row = f >> 6;                 // 0..63
            int c4 = f & 63;
            int gr = brow + row;
            if (gr > M - 1) gr = M - 1;       // clamp (masked at epilogue)
            float4 v = x4[(size_t)gr * 64 + c4];
            ushort4 u;
            u.x = f2b(v.x); u.y = f2b(v.y); u.z = f2b(v.z); u.w = f2b(v.w);
            int phys = row * 512 + (((c4 >> 1) ^ (row & 7)) << 4) + ((c4 & 1) << 3);
            *(ushort4*)(smem + phys) = u;
        }
    }
    __syncthreads();

    f32x4 acc[4][2];
    #pragma unroll
    for (int m = 0; m < 4; ++m)
        #pragma unroll
        for (int n = 0; n < 2; ++n) acc[m][n] = (f32x4){0.f, 0.f, 0.f, 0.f};

    #pragma unroll
    for (int kk = 0; kk < 8; ++kk) {
        bf16x8 a[4];
        #pragma unroll
        for (int m = 0; m < 4; ++m) {
            int row = m * 16 + lrow;
            int chunk = kk * 4 + lkc;
            a[m] = *(const bf16x8*)(smem + row * 512 + ((chunk ^ (row & 7)) << 4));
        }
        #pragma unroll
        for (int m = 0; m < 4; ++m) {
            acc[m][0] = __builtin_amdgcn_mfma_f32_16x16x32_bf16(a[m], breg[0][kk], acc[m][0], 0, 0, 0);
            acc[m][1] = __builtin_amdgcn_mfma_f32_16x16x32_bf16(a[m], breg[1][kk], acc[m][1], 0, 0, 0);
        }
    }

    // epilogue: C/D layout col=lane&15, row=(lane>>4)*4+v  (unscaled)
    #pragma unroll
    for (int m = 0; m < 4; ++m) {
        #pragma unroll
        for (int v = 0; v < 4; ++v) {
            int gr = brow + m * 16 + lkc * 4 + v;
            if (gr < M) {
                size_t rb = (size_t)gr * D_OUT;
                H[rb + wid * 32 + lrow]      = f2b(acc[m][0][v]);
                H[rb + wid * 32 + 16 + lrow] = f2b(acc[m][1][v]);
            }
        }
    }
}

// ---------------------------------------------------------------- scan (block-local exclusive) + dis
__global__ __launch_bounds__(256) void scan1_k(const unsigned long long* __restrict__ packed,
                                               int* __restrict__ row_start,
                                               int* __restrict__ blksum,
                                               float* __restrict__ dis, int N) {
    __shared__ int sdata[256];
    int t = threadIdx.x;
    int base = blockIdx.x * 1024;
    int v[4], s = 0;
    #pragma unroll
    for (int i = 0; i < 4; ++i) {
        int idx = base + t * 4 + i;
        if (idx < N) {
            unsigned long long p = packed[idx];
            v[i] = (int)(p >> 40);
            float deg = 1.0f + (float)(p & ((1ull << 40) - 1)) * (1.0f / WSCALE);
            dis[idx] = rsqrtf(deg);
        } else v[i] = 0;
        s += v[i];
    }
    sdata[t] = s;
    __syncthreads();
    #pragma unroll
    for (int off = 1; off < 256; off <<= 1) {
        int x = 0;
        if (t >= off) x = sdata[t - off];
        __syncthreads();
        sdata[t] += x;
        __syncthreads();
    }
    int excl = sdata[t] - s;
    if (t == 255) blksum[blockIdx.x] = sdata[t];
    int run = excl;
    #pragma unroll
    for (int i = 0; i < 4; ++i) {
        int idx = base + t * 4 + i;
        if (idx < N) row_start[idx] = run;
        run += v[i];
    }
}

// block-sum exclusive scan (NB <= 256). Global row start = row_start[i] + blkpre[i>>10].
__global__ __launch_bounds__(256) void scan2_k(const int* __restrict__ blksum,
                                               int* __restrict__ blkpre, int NB) {
    __shared__ int s[256];
    int t = threadIdx.x;
    int v = (t < NB) ? blksum[t] : 0;
    s[t] = v;
    __syncthreads();
    #pragma unroll
    for (int off = 1; off < 256; off <<= 1) {
        int x = 0;
        if (t >= off) x = s[t - off];
        __syncthreads();
        s[t] += x;
        __syncthreads();
    }
    if (t < NB) blkpre[t] = s[t] - v;
}

// ---------------------------------------------------------------- CSR fill (atomic-free)
// record = (src, nm) with nm = dis[src]*w*dis[dst]; slot = rowstart+blkpre+pos
__global__ void fill_k(const int* __restrict__ src, const int* __restrict__ dst,
                       const float* __restrict__ w, const int* __restrict__ pos,
                       const int* __restrict__ row_start, const int* __restrict__ blkpre,
                       const float* __restrict__ dis,
                       int2* __restrict__ csr, int E) {
    int e = blockIdx.x * blockDim.x + threadIdx.x;
    if (e >= E) return;
    int s = src[e];
    int d = dst[e];
    float nm = dis[s] * w[e] * dis[d];
    int2 rec;
    rec.x = s;
    rec.y = __float_as_int(nm);
    csr[row_start[d] + blkpre[d >> 10] + pos[e]] = rec;
}

// ---------------------------------------------------------------- aggregate + relu + pool
// Wave owns 8 contiguous nodes. Half-wave edge split: lanes 0-31 take even
// edges, 32-63 odd edges; each lane covers 4 dims (ushort4) -> 16 edges in
// flight per wave. Halves combined via shfl_xor(32) before relu/pool.
__global__ __launch_bounds__(256) void agg_pool_k(const int* __restrict__ row_start,
                                                  const int* __restrict__ blkpre,
                                                  const int2* __restrict__ csr,
                                                  const ushort* __restrict__ h,
                                                  const float* __restrict__ dis,
                                                  const float* __restrict__ bconv,
                                                  const int* __restrict__ batch,
                                                  float* __restrict__ pooled,
                                                  float* __restrict__ counts,
                                                  int N, int E) {
    int wave = threadIdx.x >> 6;
    int lane = threadIdx.x & 63;
    int half = lane >> 5;               // 0 or 1
    int hl = lane & 31;
    int c = hl * 4;                     // 4 dims per lane
    float4 b4 = *(const float4*)&bconv[c];
    int n0 = (blockIdx.x * 4 + wave) * 8;
    if (n0 >= N) return;

    float4 accp = make_float4(0.f, 0.f, 0.f, 0.f);
    int curg = -1;
    float gcount = 0.f;

    int nend = n0 + 8;
    if (nend > N) nend = N;

    int rs = row_start[n0] + blkpre[n0 >> 10];

    #pragma unroll 1
    for (int n = n0; n < nend; ++n) {
        int np = n + 1;
        int re = (np < N) ? (row_start[np] + blkpre[np >> 10]) : E;
        float din = dis[n];
        float dn2 = din * din;
        ushort4 hu = *(const ushort4*)&h[(size_t)n * D_OUT + c];
        float ax, ay, az, aw;
        if (half == 0) {                // self-loop counted once
            ax = dn2 * b2f(hu.x); ay = dn2 * b2f(hu.y);
            az = dn2 * b2f(hu.z); aw = dn2 * b2f(hu.w);
        } else {
            ax = 0.f; ay = 0.f; az = 0.f; aw = 0.f;
        }
        #pragma unroll 1
        for (int j = rs; j < re; j += 16) {
            int   idx[8];
            float nm[8];
            #pragma unroll
            for (int k = 0; k < 8; ++k) {
                int jj = j + 2 * k + half;
                int2 r = csr[jj < re ? jj : re - 1];
                idx[k] = r.x;
                nm[k] = (jj < re) ? __int_as_float(r.y) : 0.f;
            }
            ushort4 uu[8];
            #pragma unroll
            for (int k = 0; k < 8; ++k)
                uu[k] = *(const ushort4*)&h[(size_t)idx[k] * D_OUT + c];
            #pragma unroll
            for (int k = 0; k < 8; ++k) {
                ax += nm[k] * b2f(uu[k].x);
                ay += nm[k] * b2f(uu[k].y);
                az += nm[k] * b2f(uu[k].z);
                aw += nm[k] * b2f(uu[k].w);
            }
        }
        rs = re;
        // combine the two half-wave partial sums
        ax += __shfl_xor(ax, 32);
        ay += __shfl_xor(ay, 32);
        az += __shfl_xor(az, 32);
        aw += __shfl_xor(aw, 32);
        float vx = fmaxf(ax + b4.x, 0.f);
        float vy = fmaxf(ay + b4.y, 0.f);
        float vz = fmaxf(az + b4.z, 0.f);
        float vw = fmaxf(aw + b4.w, 0.f);
        int g = batch[n];
        if (g != curg) {
            if (curg >= 0 && half == 0) {
                atomicAdd(&pooled[curg * D_OUT + c],     accp.x);
                atomicAdd(&pooled[curg * D_OUT + c + 1], accp.y);
                atomicAdd(&pooled[curg * D_OUT + c + 2], accp.z);
                atomicAdd(&pooled[curg * D_OUT + c + 3], accp.w);
                if (lane == 0) atomicAdd(&counts[curg], gcount);
            }
            accp = make_float4(0.f, 0.f, 0.f, 0.f);
            gcount = 0.f;
            curg = g;
        }
        accp.x += vx; accp.y += vy; accp.z += vz; accp.w += vw;
        gcount += 1.f;
    }
    if (curg >= 0 && half == 0) {
        atomicAdd(&pooled[curg * D_OUT + c],     accp.x);
        atomicAdd(&pooled[curg * D_OUT + c + 1], accp.y);
        atomicAdd(&pooled[curg * D_OUT + c + 2], accp.z);
        atomicAdd(&pooled[curg * D_OUT + c + 3], accp.w);
        if (lane == 0) atomicAdd(&counts[curg], gcount);
    }
}

// ---------------------------------------------------------------- head
__global__ void head_k(const float* __restrict__ pooled, const float* __restrict__ counts,
                       const float* __restrict__ wlin, const float* __restrict__ blin,
                       float* __restrict__ out, int G) {
    int g = blockIdx.x;
    int lane = threadIdx.x;            // 64 threads
    float s = 0.f;
    for (int c = lane; c < D_OUT; c += 64)
        s += pooled[g * D_OUT + c] * wlin[c];
    #pragma unroll
    for (int off = 32; off; off >>= 1) s += __shfl_down(s, off);
    if (lane == 0) {
        float cnt = fmaxf(counts[g], 1.0f);
        float z = s / cnt + blin[0];
        out[g] = 1.0f / (1.0f + expf(-z));
    }
}

// ---------------------------------------------------------------- launcher
extern "C" void kernel_launch(void* const* d_in, const int* in_sizes, int n_in,
                              void* d_out, int out_size, void* d_ws, size_t ws_size,
                              hipStream_t stream) {
    const float* x     = (const float*)d_in[0];
    const int*   ei    = (const int*)  d_in[1];   // [2,E] -> src then dst
    const float* ew    = (const float*)d_in[2];
    const int*   batch = (const int*)  d_in[3];
    const float* Wc    = (const float*)d_in[4];
    const float* bc    = (const float*)d_in[5];
    const float* Wl    = (const float*)d_in[6];
    const float* bl    = (const float*)d_in[7];
    float* out = (float*)d_out;

    const int E = in_sizes[2];
    const int N = in_sizes[3];
    const int G = out_size;
    const int NB = (N + 1023) >> 10;
    const int EB = (E + 255) / 256;
    const int GB = (N + 63) / 64;

    const int* src = ei;
    const int* dst = ei + E;

    // ---- workspace layout (zero region first: packed + pooled + counts)
    unsigned long long* packed = (unsigned long long*)d_ws;   // N  (8B aligned)
    float*  pooled   = (float*)(packed + N);                  // G*128
    float*  counts   = pooled + (size_t)G * D_OUT;            // G
    // ---- rest (not zeroed)
    int*    pos      = (int*)(counts + G);                    // E
    float*  dis      = (float*)(pos + E);                     // N
    ushort* h        = (ushort*)(dis + N);                    // N*128 bf16
    ushort* Wtg      = h + (size_t)N * D_OUT;                 // 32768 bf16
    int2*   csr      = (int2*)(Wtg + D_IN * D_OUT);           // E (8B aligned)
    int*    row_start= (int*)(csr + E);                       // N
    int*    blksum   = row_start + N + 1;                     // NB
    int*    blkpre   = blksum + NB;                           // NB

    size_t zbytes = (size_t)N * 8 + ((size_t)G * D_OUT + G) * sizeof(float);
    hipMemsetAsync(packed, 0, zbytes, stream);

    wt_k      <<<(D_IN * D_OUT + 255) / 256, 256, 0, stream>>>(Wc, Wtg);

    fused_k   <<<EB + GB, 256, 32768, stream>>>(dst, ew, packed, pos, E, GB,
                                                x, Wtg, h, N);

    scan1_k   <<<NB, 256, 0, stream>>>(packed, row_start, blksum, dis, N);
    scan2_k   <<<1, 256, 0, stream>>>(blksum, blkpre, NB);

    fill_k    <<<(E + 255) / 256, 256, 0, stream>>>(src, dst, ew, pos, row_start, blkpre, dis, csr, E);

    agg_pool_k<<<(N + 31) / 32, 256, 0, stream>>>(row_start, blkpre, csr, h, dis, bc, batch,
                                                  pooled, counts, N, E);

    head_k    <<<G, 64, 0, stream>>>(pooled, counts, Wl, bl, out, G);
}

// Round 9
// 227.488 us; speedup vs baseline: 1.2365x; 1.2365x over previous
//
#include <hip/hip_runtime.h>
#include <hip/hip_bf16.h>
#include <math.h>

#define D_IN 256
#define D_OUT 128
#define WSCALE 1073741824.0f   // 2^30 fixed-point scale for edge weights

typedef __bf16 bf16x8 __attribute__((ext_vector_type(8)));
typedef float  f32x4  __attribute__((ext_vector_type(4)));
typedef float  f32x2  __attribute__((ext_vector_type(2)));

__device__ __forceinline__ float b2f(ushort u) {
    union { unsigned int i; float f; } v; v.i = ((unsigned int)u) << 16; return v.f;
}
__device__ __forceinline__ ushort f2b(float f) {   // RNE
    unsigned int x = __float_as_uint(f);
    unsigned int r = (x + 0x7FFFu + ((x >> 16) & 1u)) >> 16;
    return (ushort)r;
}
// decode 2 packed OCP e4m3 bytes -> 2 floats (HW cvt on gfx950)
__device__ __forceinline__ f32x2 fp8x2_f32(unsigned u) {
    return __builtin_amdgcn_cvt_pk_f32_fp8(u, false);
}
// encode 1 float -> 1 OCP e4m3 byte
__device__ __forceinline__ unsigned char f32_fp8(float f) {
    return (unsigned char)(__builtin_amdgcn_cvt_pk_fp8_f32(f, f, 0, false) & 0xFF);
}

// ---------------------------------------------------------------- W^T precompute (fp32 -> bf16)
__global__ void wt_k(const float* __restrict__ W, ushort* __restrict__ Wtg) {
    int t = blockIdx.x * 256 + threadIdx.x;   // 256*128 = 32768
    if (t < D_IN * D_OUT) {
        int k = t >> 7, n = t & 127;
        Wtg[n * D_IN + k] = f2b(W[t]);
    }
}

// ---------------------------------------------------------------- fused: edge atomics || MFMA GEMM
// GEMM blocks interleaved 1-in-5 so MFMA work is co-resident with the
// latency-bound edge-atomic blocks for the whole dispatch.
// H output is fp8 e4m3 (N x 128, 1 B/elem).
__global__ __launch_bounds__(256, 4) void fused_k(const int* __restrict__ dst,
                                                  const float* __restrict__ w,
                                                  unsigned long long* __restrict__ packed,
                                                  int* __restrict__ pos, int E, int GB,
                                                  const float* __restrict__ X,
                                                  const ushort* __restrict__ Wtg,
                                                  unsigned char* __restrict__ H, int M) {
    const unsigned b = blockIdx.x;
    const int g5 = b / 5;
    const bool isg = (b % 5 == 0) && (g5 < GB);
    if (!isg) {
        int ng = g5 + ((b % 5) ? 1 : 0);
        if (ng > GB) ng = GB;
        int e = (b - ng) * 256 + threadIdx.x;
        if (e < E) {
            int d = dst[e];
            unsigned long long inc = (1ull << 40) |
                (unsigned long long)(w[e] * WSCALE);
            unsigned long long old = atomicAdd(&packed[d], inc);
            pos[e] = (int)(old >> 40);
        }
        return;
    }
    // ------------- GEMM path: BM=64 rows/block, 4 waves, each wave 64 rows x 32 cols
    extern __shared__ char smem[];            // 32768 B = xs[64 rows][256 bf16] swizzled
    const int t = threadIdx.x;
    const int brow = g5 * 64;
    const int wid = t >> 6;
    const int lane = t & 63;
    const int lrow = lane & 15;
    const int lkc = lane >> 4;                // 0..3

    // preload B fragments: cols wid*32 + n*16 + lrow, k = kk*32 + lkc*8
    bf16x8 breg[2][8];
    #pragma unroll
    for (int n = 0; n < 2; ++n) {
        int col = wid * 32 + n * 16 + lrow;
        const char* base = (const char*)(Wtg + col * D_IN);
        #pragma unroll
        for (int kk = 0; kk < 8; ++kk)
            breg[n][kk] = *(const bf16x8*)(base + kk * 64 + lkc * 16);
    }

    // stage x tile: 64 rows x 256 fp32 -> bf16 LDS (16B-chunk XOR swizzle)
    {
        const float4* x4 = (const float4*)X;
        #pragma unroll
        for (int i = 0; i < 16; ++i) {
            int f = t + 256 * i;              // 4096 float4s
            int row = f >> 6;                 // 0..63
            int c4 = f & 63;
            int gr = brow + row;
            if (gr > M - 1) gr = M - 1;       // clamp (masked at epilogue)
            float4 v = x4[(size_t)gr * 64 + c4];
            ushort4 u;
            u.x = f2b(v.x); u.y = f2b(v.y); u.z = f2b(v.z); u.w = f2b(v.w);
            int phys = row * 512 + (((c4 >> 1) ^ (row & 7)) << 4) + ((c4 & 1) << 3);
            *(ushort4*)(smem + phys) = u;
        }
    }
    __syncthreads();

    f32x4 acc[4][2];
    #pragma unroll
    for (int m = 0; m < 4; ++m)
        #pragma unroll
        for (int n = 0; n < 2; ++n) acc[m][n] = (f32x4){0.f, 0.f, 0.f, 0.f};

    #pragma unroll
    for (int kk = 0; kk < 8; ++kk) {
        bf16x8 a[4];
        #pragma unroll
        for (int m = 0; m < 4; ++m) {
            int row = m * 16 + lrow;
            int chunk = kk * 4 + lkc;
            a[m] = *(const bf16x8*)(smem + row * 512 + ((chunk ^ (row & 7)) << 4));
        }
        #pragma unroll
        for (int m = 0; m < 4; ++m) {
            acc[m][0] = __builtin_amdgcn_mfma_f32_16x16x32_bf16(a[m], breg[0][kk], acc[m][0], 0, 0, 0);
            acc[m][1] = __builtin_amdgcn_mfma_f32_16x16x32_bf16(a[m], breg[1][kk], acc[m][1], 0, 0, 0);
        }
    }

    // epilogue: C/D layout col=lane&15, row=(lane>>4)*4+v  -> fp8 byte stores
    #pragma unroll
    for (int m = 0; m < 4; ++m) {
        #pragma unroll
        for (int v = 0; v < 4; ++v) {
            int gr = brow + m * 16 + lkc * 4 + v;
            if (gr < M) {
                size_t rb = (size_t)gr * D_OUT;
                H[rb + wid * 32 + lrow]      = f32_fp8(acc[m][0][v]);
                H[rb + wid * 32 + 16 + lrow] = f32_fp8(acc[m][1][v]);
            }
        }
    }
}

// ---------------------------------------------------------------- scan (block-local exclusive) + dis
__global__ __launch_bounds__(256) void scan1_k(const unsigned long long* __restrict__ packed,
                                               int* __restrict__ row_start,
                                               int* __restrict__ blksum,
                                               float* __restrict__ dis, int N) {
    __shared__ int sdata[256];
    int t = threadIdx.x;
    int base = blockIdx.x * 1024;
    int v[4], s = 0;
    #pragma unroll
    for (int i = 0; i < 4; ++i) {
        int idx = base + t * 4 + i;
        if (idx < N) {
            unsigned long long p = packed[idx];
            v[i] = (int)(p >> 40);
            float deg = 1.0f + (float)(p & ((1ull << 40) - 1)) * (1.0f / WSCALE);
            dis[idx] = rsqrtf(deg);
        } else v[i] = 0;
        s += v[i];
    }
    sdata[t] = s;
    __syncthreads();
    #pragma unroll
    for (int off = 1; off < 256; off <<= 1) {
        int x = 0;
        if (t >= off) x = sdata[t - off];
        __syncthreads();
        sdata[t] += x;
        __syncthreads();
    }
    int excl = sdata[t] - s;
    if (t == 255) blksum[blockIdx.x] = sdata[t];
    int run = excl;
    #pragma unroll
    for (int i = 0; i < 4; ++i) {
        int idx = base + t * 4 + i;
        if (idx < N) row_start[idx] = run;
        run += v[i];
    }
}

// block-sum exclusive scan (NB <= 256). Global row start = row_start[i] + blkpre[i>>10].
__global__ __launch_bounds__(256) void scan2_k(const int* __restrict__ blksum,
                                               int* __restrict__ blkpre, int NB) {
    __shared__ int s[256];
    int t = threadIdx.x;
    int v = (t < NB) ? blksum[t] : 0;
    s[t] = v;
    __syncthreads();
    #pragma unroll
    for (int off = 1; off < 256; off <<= 1) {
        int x = 0;
        if (t >= off) x = s[t - off];
        __syncthreads();
        s[t] += x;
        __syncthreads();
    }
    if (t < NB) blkpre[t] = s[t] - v;
}

// ---------------------------------------------------------------- CSR fill (atomic-free)
// record = src(17b) << 15 | bf16(nm) sans sign (15b);  nm = dis[s]*w*dis[d] > 0
__global__ void fill_k(const int* __restrict__ src, const int* __restrict__ dst,
                       const float* __restrict__ w, const int* __restrict__ pos,
                       const int* __restrict__ row_start, const int* __restrict__ blkpre,
                       const float* __restrict__ dis,
                       unsigned* __restrict__ csr, int E) {
    int e = blockIdx.x * blockDim.x + threadIdx.x;
    if (e >= E) return;
    int s = src[e];
    int d = dst[e];
    float nm = dis[s] * w[e] * dis[d];
    unsigned rec = ((unsigned)s << 15) | (f2b(nm) & 0x7FFFu);
    csr[row_start[d] + blkpre[d >> 10] + pos[e]] = rec;
}

// ---------------------------------------------------------------- aggregate + relu + pool
// R6 structure: wave owns 16 contiguous nodes, 8 edges in flight (clamped tail).
// h is fp8 e4m3 (128 B/row = 1 cache line). lane covers dims [2*lane, 2*lane+1].
// val = relu(dis^2*h[n] + sum nm*h[src] + b); pool by sorted batch.
__global__ __launch_bounds__(256) void agg_pool_k(const int* __restrict__ row_start,
                                                  const int* __restrict__ blkpre,
                                                  const unsigned* __restrict__ csr,
                                                  const unsigned char* __restrict__ h,
                                                  const float* __restrict__ dis,
                                                  const float* __restrict__ bconv,
                                                  const int* __restrict__ batch,
                                                  float* __restrict__ pooled,
                                                  float* __restrict__ counts,
                                                  int N, int E) {
    int wave = threadIdx.x >> 6;
    int lane = threadIdx.x & 63;
    int c = lane * 2;
    float2 b2 = *(const float2*)&bconv[c];
    int n0 = (blockIdx.x * 4 + wave) * 16;
    if (n0 >= N) return;

    float2 accp = make_float2(0.f, 0.f);
    int curg = -1;
    float gcount = 0.f;

    int nend = n0 + 16;
    if (nend > N) nend = N;

    int rs = row_start[n0] + blkpre[n0 >> 10];

    #pragma unroll 1
    for (int n = n0; n < nend; ++n) {
        int np = n + 1;
        int re = (np < N) ? (row_start[np] + blkpre[np >> 10]) : E;
        float din = dis[n];
        float dn2 = din * din;
        ushort su = *(const ushort*)(h + (size_t)n * D_OUT + c);
        f32x2 sv = fp8x2_f32(su);
        float ax = dn2 * sv[0];
        float ay = dn2 * sv[1];
        #pragma unroll 1
        for (int j = rs; j < re; j += 8) {
            int   idx[8];
            float nm[8];
            #pragma unroll
            for (int k = 0; k < 8; ++k) {
                int jj = j + k;
                unsigned r = csr[jj < re ? jj : re - 1];
                idx[k] = (int)(r >> 15);
                nm[k] = (jj < re) ? __uint_as_float((r & 0x7FFFu) << 16) : 0.f;
            }
            ushort uu[8];
            #pragma unroll
            for (int k = 0; k < 8; ++k)
                uu[k] = *(const ushort*)(h + (size_t)idx[k] * D_OUT + c);
            #pragma unroll
            for (int k = 0; k < 8; ++k) {
                f32x2 hv = fp8x2_f32(uu[k]);
                ax += nm[k] * hv[0];
                ay += nm[k] * hv[1];
            }
        }
        rs = re;
        float vx = fmaxf(ax + b2.x, 0.f);
        float vy = fmaxf(ay + b2.y, 0.f);
        int g = batch[n];
        if (g != curg) {
            if (curg >= 0) {
                atomicAdd(&pooled[curg * D_OUT + c],     accp.x);
                atomicAdd(&pooled[curg * D_OUT + c + 1], accp.y);
                if (lane == 0) atomicAdd(&counts[curg], gcount);
            }
            accp = make_float2(0.f, 0.f);
            gcount = 0.f;
            curg = g;
        }
        accp.x += vx;
        accp.y += vy;
        gcount += 1.f;
    }
    if (curg >= 0) {
        atomicAdd(&pooled[curg * D_OUT + c],     accp.x);
        atomicAdd(&pooled[curg * D_OUT + c + 1], accp.y);
        if (lane == 0) atomicAdd(&counts[curg], gcount);
    }
}

// ---------------------------------------------------------------- head
__global__ void head_k(const float* __restrict__ pooled, const float* __restrict__ counts,
                       const float* __restrict__ wlin, const float* __restrict__ blin,
                       float* __restrict__ out, int G) {
    int g = blockIdx.x;
    int lane = threadIdx.x;            // 64 threads
    float s = 0.f;
    for (int c = lane; c < D_OUT; c += 64)
        s += pooled[g * D_OUT + c] * wlin[c];
    #pragma unroll
    for (int off = 32; off; off >>= 1) s += __shfl_down(s, off);
    if (lane == 0) {
        float cnt = fmaxf(counts[g], 1.0f);
        float z = s / cnt + blin[0];
        out[g] = 1.0f / (1.0f + expf(-z));
    }
}

// ---------------------------------------------------------------- launcher
extern "C" void kernel_launch(void* const* d_in, const int* in_sizes, int n_in,
                              void* d_out, int out_size, void* d_ws, size_t ws_size,
                              hipStream_t stream) {
    const float* x     = (const float*)d_in[0];
    const int*   ei    = (const int*)  d_in[1];   // [2,E] -> src then dst
    const float* ew    = (const float*)d_in[2];
    const int*   batch = (const int*)  d_in[3];
    const float* Wc    = (const float*)d_in[4];
    const float* bc    = (const float*)d_in[5];
    const float* Wl    = (const float*)d_in[6];
    const float* bl    = (const float*)d_in[7];
    float* out = (float*)d_out;

    const int E = in_sizes[2];
    const int N = in_sizes[3];
    const int G = out_size;
    const int NB = (N + 1023) >> 10;
    const int EB = (E + 255) / 256;
    const int GB = (N + 63) / 64;

    const int* src = ei;
    const int* dst = ei + E;

    // ---- workspace layout (zero region first: packed + pooled + counts)
    unsigned long long* packed = (unsigned long long*)d_ws;   // N  (8B aligned)
    float*  pooled   = (float*)(packed + N);                  // G*128
    float*  counts   = pooled + (size_t)G * D_OUT;            // G
    // ---- rest (not zeroed)
    int*    pos      = (int*)(counts + G);                    // E
    float*  dis      = (float*)(pos + E);                     // N
    unsigned char* h = (unsigned char*)(dis + N);             // N*128 fp8
    ushort* Wtg      = (ushort*)(h + (size_t)N * D_OUT);      // 32768 bf16
    unsigned* csr    = (unsigned*)(Wtg + D_IN * D_OUT);       // E (4B)
    int*    row_start= (int*)(csr + E);                       // N
    int*    blksum   = row_start + N + 1;                     // NB
    int*    blkpre   = blksum + NB;                           // NB

    size_t zbytes = (size_t)N * 8 + ((size_t)G * D_OUT + G) * sizeof(float);
    hipMemsetAsync(packed, 0, zbytes, stream);

    wt_k      <<<(D_IN * D_OUT + 255) / 256, 256, 0, stream>>>(Wc, Wtg);

    fused_k   <<<EB + GB, 256, 32768, stream>>>(dst, ew, packed, pos, E, GB,
                                                x, Wtg, h, N);

    scan1_k   <<<NB, 256, 0, stream>>>(packed, row_start, blksum, dis, N);
    scan2_k   <<<1, 256, 0, stream>>>(blksum, blkpre, NB);

    fill_k    <<<(E + 255) / 256, 256, 0, stream>>>(src, dst, ew, pos, row_start, blkpre, dis, csr, E);

    agg_pool_k<<<(N + 63) / 64, 256, 0, stream>>>(row_start, blkpre, csr, h, dis, bc, batch,
                                                  pooled, counts, N, E);

    head_k    <<<G, 64, 0, stream>>>(pooled, counts, Wl, bl, out, G);
}

// Round 10
// 212.778 us; speedup vs baseline: 1.3220x; 1.0691x over previous
//
#include <hip/hip_runtime.h>
#include <hip/hip_bf16.h>
#include <math.h>

#define D_IN 256
#define D_OUT 128
#define WSCALE 1073741824.0f   // 2^30 fixed-point scale for edge weights

typedef __bf16 bf16x8 __attribute__((ext_vector_type(8)));
typedef float  f32x4  __attribute__((ext_vector_type(4)));
typedef float  f32x2  __attribute__((ext_vector_type(2)));

__device__ __forceinline__ ushort f2b(float f) {   // RNE
    unsigned int x = __float_as_uint(f);
    unsigned int r = (x + 0x7FFFu + ((x >> 16) & 1u)) >> 16;
    return (ushort)r;
}
// decode 2 packed OCP e4m3 bytes -> 2 floats (HW cvt on gfx950)
__device__ __forceinline__ f32x2 fp8x2_f32(unsigned u) {
    return __builtin_amdgcn_cvt_pk_f32_fp8(u, false);
}
// encode 1 float -> 1 OCP e4m3 byte
__device__ __forceinline__ unsigned char f32_fp8(float f) {
    return (unsigned char)(__builtin_amdgcn_cvt_pk_fp8_f32(f, f, 0, false) & 0xFF);
}

// ---------------------------------------------------------------- W^T precompute (fp32 -> bf16)
__global__ void wt_k(const float* __restrict__ W, ushort* __restrict__ Wtg) {
    int t = blockIdx.x * 256 + threadIdx.x;   // 256*128 = 32768
    if (t < D_IN * D_OUT) {
        int k = t >> 7, n = t & 127;
        Wtg[n * D_IN + k] = f2b(W[t]);
    }
}

// ---------------------------------------------------------------- fused: edge atomics || MFMA GEMM
// GEMM blocks interleaved 1-in-5 so MFMA work is co-resident with the
// latency-bound edge-atomic blocks for the whole dispatch.
// H output is fp8 e4m3 (N x 128, 1 B/elem).
__global__ __launch_bounds__(256, 4) void fused_k(const int* __restrict__ dst,
                                                  const float* __restrict__ w,
                                                  unsigned long long* __restrict__ packed,
                                                  int* __restrict__ pos, int E, int GB,
                                                  const float* __restrict__ X,
                                                  const ushort* __restrict__ Wtg,
                                                  unsigned char* __restrict__ H, int M) {
    const unsigned b = blockIdx.x;
    const int g5 = b / 5;
    const bool isg = (b % 5 == 0) && (g5 < GB);
    if (!isg) {
        int ng = g5 + ((b % 5) ? 1 : 0);
        if (ng > GB) ng = GB;
        int e = (b - ng) * 256 + threadIdx.x;
        if (e < E) {
            int d = dst[e];
            unsigned long long inc = (1ull << 40) |
                (unsigned long long)(w[e] * WSCALE);
            unsigned long long old = atomicAdd(&packed[d], inc);
            pos[e] = (int)(old >> 40);
        }
        return;
    }
    // ------------- GEMM path: BM=64 rows/block, 4 waves, each wave 64 rows x 32 cols
    extern __shared__ char smem[];            // 32768 B = xs[64 rows][256 bf16] swizzled
    const int t = threadIdx.x;
    const int brow = g5 * 64;
    const int wid = t >> 6;
    const int lane = t & 63;
    const int lrow = lane & 15;
    const int lkc = lane >> 4;                // 0..3

    // preload B fragments: cols wid*32 + n*16 + lrow, k = kk*32 + lkc*8
    bf16x8 breg[2][8];
    #pragma unroll
    for (int n = 0; n < 2; ++n) {
        int col = wid * 32 + n * 16 + lrow;
        const char* base = (const char*)(Wtg + col * D_IN);
        #pragma unroll
        for (int kk = 0; kk < 8; ++kk)
            breg[n][kk] = *(const bf16x8*)(base + kk * 64 + lkc * 16);
    }

    // stage x tile: 64 rows x 256 fp32 -> bf16 LDS (16B-chunk XOR swizzle)
    {
        const float4* x4 = (const float4*)X;
        #pragma unroll
        for (int i = 0; i < 16; ++i) {
            int f = t + 256 * i;              // 4096 float4s
            int row = f >> 6;                 // 0..63
            int c4 = f & 63;
            int gr = brow + row;
            if (gr > M - 1) gr = M - 1;       // clamp (masked at epilogue)
            float4 v = x4[(size_t)gr * 64 + c4];
            ushort4 u;
            u.x = f2b(v.x); u.y = f2b(v.y); u.z = f2b(v.z); u.w = f2b(v.w);
            int phys = row * 512 + (((c4 >> 1) ^ (row & 7)) << 4) + ((c4 & 1) << 3);
            *(ushort4*)(smem + phys) = u;
        }
    }
    __syncthreads();

    f32x4 acc[4][2];
    #pragma unroll
    for (int m = 0; m < 4; ++m)
        #pragma unroll
        for (int n = 0; n < 2; ++n) acc[m][n] = (f32x4){0.f, 0.f, 0.f, 0.f};

    #pragma unroll
    for (int kk = 0; kk < 8; ++kk) {
        bf16x8 a[4];
        #pragma unroll
        for (int m = 0; m < 4; ++m) {
            int row = m * 16 + lrow;
            int chunk = kk * 4 + lkc;
            a[m] = *(const bf16x8*)(smem + row * 512 + ((chunk ^ (row & 7)) << 4));
        }
        #pragma unroll
        for (int m = 0; m < 4; ++m) {
            acc[m][0] = __builtin_amdgcn_mfma_f32_16x16x32_bf16(a[m], breg[0][kk], acc[m][0], 0, 0, 0);
            acc[m][1] = __builtin_amdgcn_mfma_f32_16x16x32_bf16(a[m], breg[1][kk], acc[m][1], 0, 0, 0);
        }
    }

    // epilogue: C/D layout col=lane&15, row=(lane>>4)*4+v  -> fp8 byte stores
    #pragma unroll
    for (int m = 0; m < 4; ++m) {
        #pragma unroll
        for (int v = 0; v < 4; ++v) {
            int gr = brow + m * 16 + lkc * 4 + v;
            if (gr < M) {
                size_t rb = (size_t)gr * D_OUT;
                H[rb + wid * 32 + lrow]      = f32_fp8(acc[m][0][v]);
                H[rb + wid * 32 + 16 + lrow] = f32_fp8(acc[m][1][v]);
            }
        }
    }
}

// ---------------------------------------------------------------- scan (block-local exclusive, PADDED) + dis
// Row allocations are padded to multiples of 8 records so agg rows are
// 32B-aligned and tail-clamp-free (pad records are zeroed -> contribute 0).
__global__ __launch_bounds__(256) void scan1_k(const unsigned long long* __restrict__ packed,
                                               int* __restrict__ row_start,
                                               int* __restrict__ blksum,
                                               float* __restrict__ dis, int N) {
    __shared__ int sdata[256];
    int t = threadIdx.x;
    int base = blockIdx.x * 1024;
    int v[4], s = 0;
    #pragma unroll
    for (int i = 0; i < 4; ++i) {
        int idx = base + t * 4 + i;
        if (idx < N) {
            unsigned long long p = packed[idx];
            int cnt = (int)(p >> 40);
            float deg = 1.0f + (float)(p & ((1ull << 40) - 1)) * (1.0f / WSCALE);
            dis[idx] = rsqrtf(deg);
            v[i] = (cnt + 7) & ~7;        // padded row size
        } else v[i] = 0;
        s += v[i];
    }
    sdata[t] = s;
    __syncthreads();
    #pragma unroll
    for (int off = 1; off < 256; off <<= 1) {
        int x = 0;
        if (t >= off) x = sdata[t - off];
        __syncthreads();
        sdata[t] += x;
        __syncthreads();
    }
    int excl = sdata[t] - s;
    if (t == 255) blksum[blockIdx.x] = sdata[t];
    int run = excl;
    #pragma unroll
    for (int i = 0; i < 4; ++i) {
        int idx = base + t * 4 + i;
        if (idx < N) row_start[idx] = run;
        run += v[i];
    }
}

// block-sum exclusive scan (NB <= 256); also writes global padded total to row_start[N].
__global__ __launch_bounds__(256) void scan2_k(const int* __restrict__ blksum,
                                               int* __restrict__ blkpre, int NB,
                                               int* __restrict__ row_start, int N) {
    __shared__ int s[256];
    int t = threadIdx.x;
    int v = (t < NB) ? blksum[t] : 0;
    s[t] = v;
    __syncthreads();
    #pragma unroll
    for (int off = 1; off < 256; off <<= 1) {
        int x = 0;
        if (t >= off) x = s[t - off];
        __syncthreads();
        s[t] += x;
        __syncthreads();
    }
    if (t < NB) blkpre[t] = s[t] - v;
    if (t == NB - 1) row_start[N] = s[t];   // global padded total
}

// ---------------------------------------------------------------- CSR fill (atomic-free)
// record = src(17b) << 15 | bf16(nm) sans sign (15b);  nm = dis[s]*w*dis[d] > 0
__global__ void fill_k(const int* __restrict__ src, const int* __restrict__ dst,
                       const float* __restrict__ w, const int* __restrict__ pos,
                       const int* __restrict__ row_start, const int* __restrict__ blkpre,
                       const float* __restrict__ dis,
                       unsigned* __restrict__ csr, int E) {
    int e = blockIdx.x * blockDim.x + threadIdx.x;
    if (e >= E) return;
    int s = src[e];
    int d = dst[e];
    float nm = dis[s] * w[e] * dis[d];
    unsigned rec = ((unsigned)s << 15) | (f2b(nm) & 0x7FFFu);
    csr[row_start[d] + blkpre[d >> 10] + pos[e]] = rec;
}

// ---------------------------------------------------------------- aggregate + relu + pool
// Wave owns 16 contiguous nodes. Rows padded to x8 -> inner loop is clamp-free:
// 8 records come in as two broadcast uint4 loads; pad records are 0 (nm=0).
// h is fp8 e4m3 (128 B/row). lane covers dims [2*lane, 2*lane+1].
// val = relu(dis^2*h[n] + sum nm*h[src] + b); pool by sorted batch.
__global__ __launch_bounds__(256) void agg_pool_k(const int* __restrict__ row_start,
                                                  const int* __restrict__ blkpre,
                                                  const unsigned* __restrict__ csr,
                                                  const unsigned char* __restrict__ h,
                                                  const float* __restrict__ dis,
                                                  const float* __restrict__ bconv,
                                                  const int* __restrict__ batch,
                                                  float* __restrict__ pooled,
                                                  float* __restrict__ counts, int N) {
    int wave = threadIdx.x >> 6;
    int lane = threadIdx.x & 63;
    int c = lane * 2;                   // byte offset into 128B fp8 row
    float2 b2 = *(const float2*)&bconv[c];
    int n0 = (blockIdx.x * 4 + wave) * 16;
    if (n0 >= N) return;

    float2 accp = make_float2(0.f, 0.f);
    int curg = -1;
    float gcount = 0.f;

    int nend = n0 + 16;
    if (nend > N) nend = N;

    int rs = row_start[n0] + blkpre[n0 >> 10];

    #pragma unroll 1
    for (int n = n0; n < nend; ++n) {
        int np = n + 1;
        int re = row_start[np] + ((np < N) ? blkpre[np >> 10] : 0);  // row_start[N]=total
        float din = dis[n];
        float dn2 = din * din;
        ushort su = *(const ushort*)(h + (size_t)n * D_OUT + c);
        f32x2 sv = fp8x2_f32(su);
        float ax = dn2 * sv[0];
        float ay = dn2 * sv[1];
        #pragma unroll 1
        for (int j = rs; j < re; j += 8) {
            uint4 ra = *(const uint4*)(csr + j);       // 32B-aligned (rows padded to x8)
            uint4 rb = *(const uint4*)(csr + j + 4);
            unsigned rc[8] = {ra.x, ra.y, ra.z, ra.w, rb.x, rb.y, rb.z, rb.w};
            ushort uu[8];
            float nm[8];
            #pragma unroll
            for (int k = 0; k < 8; ++k) {
                nm[k] = __uint_as_float((rc[k] & 0x7FFFu) << 16);
                uu[k] = *(const ushort*)(h + (size_t)((rc[k] >> 15) << 7) + c);
            }
            #pragma unroll
            for (int k = 0; k < 8; ++k) {
                f32x2 hv = fp8x2_f32(uu[k]);
                ax += nm[k] * hv[0];
                ay += nm[k] * hv[1];
            }
        }
        rs = re;
        float vx = fmaxf(ax + b2.x, 0.f);
        float vy = fmaxf(ay + b2.y, 0.f);
        int g = batch[n];
        if (g != curg) {
            if (curg >= 0) {
                atomicAdd(&pooled[curg * D_OUT + c],     accp.x);
                atomicAdd(&pooled[curg * D_OUT + c + 1], accp.y);
                if (lane == 0) atomicAdd(&counts[curg], gcount);
            }
            accp = make_float2(0.f, 0.f);
            gcount = 0.f;
            curg = g;
        }
        accp.x += vx;
        accp.y += vy;
        gcount += 1.f;
    }
    if (curg >= 0) {
        atomicAdd(&pooled[curg * D_OUT + c],     accp.x);
        atomicAdd(&pooled[curg * D_OUT + c + 1], accp.y);
        if (lane == 0) atomicAdd(&counts[curg], gcount);
    }
}

// ---------------------------------------------------------------- head
__global__ void head_k(const float* __restrict__ pooled, const float* __restrict__ counts,
                       const float* __restrict__ wlin, const float* __restrict__ blin,
                       float* __restrict__ out, int G) {
    int g = blockIdx.x;
    int lane = threadIdx.x;            // 64 threads
    float s = 0.f;
    for (int c = lane; c < D_OUT; c += 64)
        s += pooled[g * D_OUT + c] * wlin[c];
    #pragma unroll
    for (int off = 32; off; off >>= 1) s += __shfl_down(s, off);
    if (lane == 0) {
        float cnt = fmaxf(counts[g], 1.0f);
        float z = s / cnt + blin[0];
        out[g] = 1.0f / (1.0f + expf(-z));
    }
}

// ---------------------------------------------------------------- launcher
extern "C" void kernel_launch(void* const* d_in, const int* in_sizes, int n_in,
                              void* d_out, int out_size, void* d_ws, size_t ws_size,
                              hipStream_t stream) {
    const float* x     = (const float*)d_in[0];
    const int*   ei    = (const int*)  d_in[1];   // [2,E] -> src then dst
    const float* ew    = (const float*)d_in[2];
    const int*   batch = (const int*)  d_in[3];
    const float* Wc    = (const float*)d_in[4];
    const float* bc    = (const float*)d_in[5];
    const float* Wl    = (const float*)d_in[6];
    const float* bl    = (const float*)d_in[7];
    float* out = (float*)d_out;

    const int E = in_sizes[2];
    const int N = in_sizes[3];
    const int G = out_size;
    const int NB = (N + 1023) >> 10;
    const int EB = (E + 255) / 256;
    const int GB = (N + 63) / 64;
    const int CSR_CAP = E + 8 * N;     // worst-case padded

    const int* src = ei;
    const int* dst = ei + E;

    // ---- workspace layout: zeroed-every-call region first
    unsigned long long* packed = (unsigned long long*)d_ws;   // N (8B aligned)
    float*  pooled   = (float*)(packed + N);                  // G*128
    float*  counts   = pooled + (size_t)G * D_OUT;            // G
    unsigned* csr    = (unsigned*)(counts + G);               // E + 8N (zeroed -> pads are 0)
    // ---- rest (not zeroed)
    int*    pos      = (int*)(csr + CSR_CAP);                 // E
    float*  dis      = (float*)(pos + E);                     // N
    unsigned char* h = (unsigned char*)(dis + N);             // N*128 fp8
    ushort* Wtg      = (ushort*)(h + (size_t)N * D_OUT);      // 32768 bf16
    int*    row_start= (int*)(Wtg + D_IN * D_OUT);            // N+1
    int*    blksum   = row_start + N + 1;                     // NB
    int*    blkpre   = blksum + NB;                           // NB

    size_t zbytes = (size_t)N * 8 + ((size_t)G * D_OUT + G) * sizeof(float)
                  + (size_t)CSR_CAP * sizeof(unsigned);
    hipMemsetAsync(packed, 0, zbytes, stream);

    wt_k      <<<(D_IN * D_OUT + 255) / 256, 256, 0, stream>>>(Wc, Wtg);

    fused_k   <<<EB + GB, 256, 32768, stream>>>(dst, ew, packed, pos, E, GB,
                                                x, Wtg, h, N);

    scan1_k   <<<NB, 256, 0, stream>>>(packed, row_start, blksum, dis, N);
    scan2_k   <<<1, 256, 0, stream>>>(blksum, blkpre, NB, row_start, N);

    fill_k    <<<(E + 255) / 256, 256, 0, stream>>>(src, dst, ew, pos, row_start, blkpre, dis, csr, E);

    agg_pool_k<<<(N + 63) / 64, 256, 0, stream>>>(row_start, blkpre, csr, h, dis, bc, batch,
                                                  pooled, counts, N);

    head_k    <<<G, 64, 0, stream>>>(pooled, counts, Wl, bl, out, G);
}

// Round 11
// 210.835 us; speedup vs baseline: 1.3341x; 1.0092x over previous
//
#include <hip/hip_runtime.h>
#include <hip/hip_bf16.h>
#include <math.h>

#define D_IN 256
#define D_OUT 128
#define WSCALE 1073741824.0f   // 2^30 fixed-point scale for edge weights

typedef __bf16 bf16x8 __attribute__((ext_vector_type(8)));
typedef float  f32x4  __attribute__((ext_vector_type(4)));
typedef float  f32x2  __attribute__((ext_vector_type(2)));

__device__ __forceinline__ ushort f2b(float f) {   // RNE
    unsigned int x = __float_as_uint(f);
    unsigned int r = (x + 0x7FFFu + ((x >> 16) & 1u)) >> 16;
    return (ushort)r;
}
// decode 2 packed OCP e4m3 bytes -> 2 floats (HW cvt on gfx950)
__device__ __forceinline__ f32x2 fp8x2_f32(unsigned u) {
    return __builtin_amdgcn_cvt_pk_f32_fp8(u, false);
}
// encode 1 float -> 1 OCP e4m3 byte
__device__ __forceinline__ unsigned char f32_fp8(float f) {
    return (unsigned char)(__builtin_amdgcn_cvt_pk_fp8_f32(f, f, 0, false) & 0xFF);
}

// ---------------------------------------------------------------- W^T precompute (fp32 -> bf16)
__global__ void wt_k(const float* __restrict__ W, ushort* __restrict__ Wtg) {
    int t = blockIdx.x * 256 + threadIdx.x;   // 256*128 = 32768
    if (t < D_IN * D_OUT) {
        int k = t >> 7, n = t & 127;
        Wtg[n * D_IN + k] = f2b(W[t]);
    }
}

// ---------------------------------------------------------------- fused: edge atomics || MFMA GEMM
// 1:1 interleave (even blocks = GEMM, odd = edges). Edge blocks cover 1024
// edges each, 4 per thread (independent atomics -> 4x in-flight per wave).
// One 64-bit atomic per edge: count<<40 | fixedpoint wsum; old count = slot.
// H output is fp8 e4m3 (N x 128, 1 B/elem).
__global__ __launch_bounds__(256, 4) void fused_k(const int* __restrict__ dst,
                                                  const float* __restrict__ w,
                                                  unsigned long long* __restrict__ packed,
                                                  int* __restrict__ pos, int E, int GB,
                                                  const float* __restrict__ X,
                                                  const ushort* __restrict__ Wtg,
                                                  unsigned char* __restrict__ H, int M) {
    const int b = (int)blockIdx.x;
    const bool isg = ((b & 1) == 0) && ((b >> 1) < GB);
    if (!isg) {
        int gb_before = (b + 1) >> 1;
        if (gb_before > GB) gb_before = GB;
        int e0 = (b - gb_before) * 1024 + (int)threadIdx.x;
        #pragma unroll
        for (int i = 0; i < 4; ++i) {
            int e = e0 + i * 256;
            if (e < E) {
                int d = dst[e];
                unsigned long long inc = (1ull << 40) |
                    (unsigned long long)(w[e] * WSCALE);
                unsigned long long old = atomicAdd(&packed[d], inc);
                pos[e] = (int)(old >> 40);
            }
        }
        return;
    }
    // ------------- GEMM path: BM=64 rows/block, 4 waves, each wave 64 rows x 32 cols
    extern __shared__ char smem[];            // 32768 B = xs[64 rows][256 bf16] swizzled
    const int t = threadIdx.x;
    const int brow = (b >> 1) * 64;
    const int wid = t >> 6;
    const int lane = t & 63;
    const int lrow = lane & 15;
    const int lkc = lane >> 4;                // 0..3

    // preload B fragments: cols wid*32 + n*16 + lrow, k = kk*32 + lkc*8
    bf16x8 breg[2][8];
    #pragma unroll
    for (int n = 0; n < 2; ++n) {
        int col = wid * 32 + n * 16 + lrow;
        const char* base = (const char*)(Wtg + col * D_IN);
        #pragma unroll
        for (int kk = 0; kk < 8; ++kk)
            breg[n][kk] = *(const bf16x8*)(base + kk * 64 + lkc * 16);
    }

    // stage x tile: 64 rows x 256 fp32 -> bf16 LDS (16B-chunk XOR swizzle)
    {
        const float4* x4 = (const float4*)X;
        #pragma unroll
        for (int i = 0; i < 16; ++i) {
            int f = t + 256 * i;              // 4096 float4s
            int row = f >> 6;                 // 0..63
            int c4 = f & 63;
            int gr = brow + row;
            if (gr > M - 1) gr = M - 1;       // clamp (masked at epilogue)
            float4 v = x4[(size_t)gr * 64 + c4];
            ushort4 u;
            u.x = f2b(v.x); u.y = f2b(v.y); u.z = f2b(v.z); u.w = f2b(v.w);
            int phys = row * 512 + (((c4 >> 1) ^ (row & 7)) << 4) + ((c4 & 1) << 3);
            *(ushort4*)(smem + phys) = u;
        }
    }
    __syncthreads();

    f32x4 acc[4][2];
    #pragma unroll
    for (int m = 0; m < 4; ++m)
        #pragma unroll
        for (int n = 0; n < 2; ++n) acc[m][n] = (f32x4){0.f, 0.f, 0.f, 0.f};

    #pragma unroll
    for (int kk = 0; kk < 8; ++kk) {
        bf16x8 a[4];
        #pragma unroll
        for (int m = 0; m < 4; ++m) {
            int row = m * 16 + lrow;
            int chunk = kk * 4 + lkc;
            a[m] = *(const bf16x8*)(smem + row * 512 + ((chunk ^ (row & 7)) << 4));
        }
        #pragma unroll
        for (int m = 0; m < 4; ++m) {
            acc[m][0] = __builtin_amdgcn_mfma_f32_16x16x32_bf16(a[m], breg[0][kk], acc[m][0], 0, 0, 0);
            acc[m][1] = __builtin_amdgcn_mfma_f32_16x16x32_bf16(a[m], breg[1][kk], acc[m][1], 0, 0, 0);
        }
    }

    // epilogue: C/D layout col=lane&15, row=(lane>>4)*4+v  -> fp8 byte stores
    #pragma unroll
    for (int m = 0; m < 4; ++m) {
        #pragma unroll
        for (int v = 0; v < 4; ++v) {
            int gr = brow + m * 16 + lkc * 4 + v;
            if (gr < M) {
                size_t rb = (size_t)gr * D_OUT;
                H[rb + wid * 32 + lrow]      = f32_fp8(acc[m][0][v]);
                H[rb + wid * 32 + 16 + lrow] = f32_fp8(acc[m][1][v]);
            }
        }
    }
}

// ---------------------------------------------------------------- scan (block-local exclusive, PADDED) + dis
// Row allocations padded to multiples of 8 records: agg rows 32B-aligned,
// tail-clamp-free (pad records zeroed -> contribute 0).
__global__ __launch_bounds__(256) void scan1_k(const unsigned long long* __restrict__ packed,
                                               int* __restrict__ row_start,
                                               int* __restrict__ blksum,
                                               float* __restrict__ dis, int N) {
    __shared__ int sdata[256];
    int t = threadIdx.x;
    int base = blockIdx.x * 1024;
    int v[4], s = 0;
    #pragma unroll
    for (int i = 0; i < 4; ++i) {
        int idx = base + t * 4 + i;
        if (idx < N) {
            unsigned long long p = packed[idx];
            int cnt = (int)(p >> 40);
            float deg = 1.0f + (float)(p & ((1ull << 40) - 1)) * (1.0f / WSCALE);
            dis[idx] = rsqrtf(deg);
            v[i] = (cnt + 7) & ~7;        // padded row size
        } else v[i] = 0;
        s += v[i];
    }
    sdata[t] = s;
    __syncthreads();
    #pragma unroll
    for (int off = 1; off < 256; off <<= 1) {
        int x = 0;
        if (t >= off) x = sdata[t - off];
        __syncthreads();
        sdata[t] += x;
        __syncthreads();
    }
    int excl = sdata[t] - s;
    if (t == 255) blksum[blockIdx.x] = sdata[t];
    int run = excl;
    #pragma unroll
    for (int i = 0; i < 4; ++i) {
        int idx = base + t * 4 + i;
        if (idx < N) row_start[idx] = run;
        run += v[i];
    }
}

// block-sum exclusive scan (NB <= 256); also writes global padded total to row_start[N].
__global__ __launch_bounds__(256) void scan2_k(const int* __restrict__ blksum,
                                               int* __restrict__ blkpre, int NB,
                                               int* __restrict__ row_start, int N) {
    __shared__ int s[256];
    int t = threadIdx.x;
    int v = (t < NB) ? blksum[t] : 0;
    s[t] = v;
    __syncthreads();
    #pragma unroll
    for (int off = 1; off < 256; off <<= 1) {
        int x = 0;
        if (t >= off) x = s[t - off];
        __syncthreads();
        s[t] += x;
        __syncthreads();
    }
    if (t < NB) blkpre[t] = s[t] - v;
    if (t == NB - 1) row_start[N] = s[t];   // global padded total
}

// ---------------------------------------------------------------- CSR fill (atomic-free)
// record = src(17b) << 15 | bf16(nm) sans sign (15b);  nm = dis[s]*w*dis[d] > 0
__global__ void fill_k(const int* __restrict__ src, const int* __restrict__ dst,
                       const float* __restrict__ w, const int* __restrict__ pos,
                       const int* __restrict__ row_start, const int* __restrict__ blkpre,
                       const float* __restrict__ dis,
                       unsigned* __restrict__ csr, int E) {
    int e = blockIdx.x * blockDim.x + threadIdx.x;
    if (e >= E) return;
    int s = src[e];
    int d = dst[e];
    float nm = dis[s] * w[e] * dis[d];
    unsigned rec = ((unsigned)s << 15) | (f2b(nm) & 0x7FFFu);
    csr[row_start[d] + blkpre[d >> 10] + pos[e]] = rec;
}

// ---------------------------------------------------------------- aggregate + relu + pool
// Wave owns 16 contiguous nodes. Rows padded to x8 -> clamp-free inner loop:
// 8 records = two broadcast uint4 loads; pad records are 0 (nm=0).
// h is fp8 e4m3 (128 B/row). lane covers dims [2*lane, 2*lane+1].
// val = relu(dis^2*h[n] + sum nm*h[src] + b); pool by sorted batch.
__global__ __launch_bounds__(256) void agg_pool_k(const int* __restrict__ row_start,
                                                  const int* __restrict__ blkpre,
                                                  const unsigned* __restrict__ csr,
                                                  const unsigned char* __restrict__ h,
                                                  const float* __restrict__ dis,
                                                  const float* __restrict__ bconv,
                                                  const int* __restrict__ batch,
                                                  float* __restrict__ pooled,
                                                  float* __restrict__ counts, int N) {
    int wave = threadIdx.x >> 6;
    int lane = threadIdx.x & 63;
    int c = lane * 2;                   // byte offset into 128B fp8 row
    float2 b2 = *(const float2*)&bconv[c];
    int n0 = (blockIdx.x * 4 + wave) * 16;
    if (n0 >= N) return;

    float2 accp = make_float2(0.f, 0.f);
    int curg = -1;
    float gcount = 0.f;

    int nend = n0 + 16;
    if (nend > N) nend = N;

    int rs = row_start[n0] + blkpre[n0 >> 10];

    #pragma unroll 1
    for (int n = n0; n < nend; ++n) {
        int np = n + 1;
        int re = row_start[np] + ((np < N) ? blkpre[np >> 10] : 0);  // row_start[N]=total
        float din = dis[n];
        float dn2 = din * din;
        ushort su = *(const ushort*)(h + (size_t)n * D_OUT + c);
        f32x2 sv = fp8x2_f32(su);
        float ax = dn2 * sv[0];
        float ay = dn2 * sv[1];
        #pragma unroll 1
        for (int j = rs; j < re; j += 8) {
            uint4 ra = *(const uint4*)(csr + j);       // 32B-aligned (rows padded to x8)
            uint4 rb = *(const uint4*)(csr + j + 4);
            unsigned rc[8] = {ra.x, ra.y, ra.z, ra.w, rb.x, rb.y, rb.z, rb.w};
            ushort uu[8];
            float nm[8];
            #pragma unroll
            for (int k = 0; k < 8; ++k) {
                nm[k] = __uint_as_float((rc[k] & 0x7FFFu) << 16);
                uu[k] = *(const ushort*)(h + (size_t)((rc[k] >> 15) << 7) + c);
            }
            #pragma unroll
            for (int k = 0; k < 8; ++k) {
                f32x2 hv = fp8x2_f32(uu[k]);
                ax += nm[k] * hv[0];
                ay += nm[k] * hv[1];
            }
        }
        rs = re;
        float vx = fmaxf(ax + b2.x, 0.f);
        float vy = fmaxf(ay + b2.y, 0.f);
        int g = batch[n];
        if (g != curg) {
            if (curg >= 0) {
                atomicAdd(&pooled[curg * D_OUT + c],     accp.x);
                atomicAdd(&pooled[curg * D_OUT + c + 1], accp.y);
                if (lane == 0) atomicAdd(&counts[curg], gcount);
            }
            accp = make_float2(0.f, 0.f);
            gcount = 0.f;
            curg = g;
        }
        accp.x += vx;
        accp.y += vy;
        gcount += 1.f;
    }
    if (curg >= 0) {
        atomicAdd(&pooled[curg * D_OUT + c],     accp.x);
        atomicAdd(&pooled[curg * D_OUT + c + 1], accp.y);
        if (lane == 0) atomicAdd(&counts[curg], gcount);
    }
}

// ---------------------------------------------------------------- head
__global__ void head_k(const float* __restrict__ pooled, const float* __restrict__ counts,
                       const float* __restrict__ wlin, const float* __restrict__ blin,
                       float* __restrict__ out, int G) {
    int g = blockIdx.x;
    int lane = threadIdx.x;            // 64 threads
    float s = 0.f;
    for (int c = lane; c < D_OUT; c += 64)
        s += pooled[g * D_OUT + c] * wlin[c];
    #pragma unroll
    for (int off = 32; off; off >>= 1) s += __shfl_down(s, off);
    if (lane == 0) {
        float cnt = fmaxf(counts[g], 1.0f);
        float z = s / cnt + blin[0];
        out[g] = 1.0f / (1.0f + expf(-z));
    }
}

// ---------------------------------------------------------------- launcher
extern "C" void kernel_launch(void* const* d_in, const int* in_sizes, int n_in,
                              void* d_out, int out_size, void* d_ws, size_t ws_size,
                              hipStream_t stream) {
    const float* x     = (const float*)d_in[0];
    const int*   ei    = (const int*)  d_in[1];   // [2,E] -> src then dst
    const float* ew    = (const float*)d_in[2];
    const int*   batch = (const int*)  d_in[3];
    const float* Wc    = (const float*)d_in[4];
    const float* bc    = (const float*)d_in[5];
    const float* Wl    = (const float*)d_in[6];
    const float* bl    = (const float*)d_in[7];
    float* out = (float*)d_out;

    const int E = in_sizes[2];
    const int N = in_sizes[3];
    const int G = out_size;
    const int NB = (N + 1023) >> 10;
    const int EB = (E + 1023) / 1024;  // edge blocks (4 edges/thread)
    const int GB = (N + 63) / 64;
    const int CSR_CAP = E + 8 * N;     // worst-case padded

    const int* src = ei;
    const int* dst = ei + E;

    // ---- workspace layout: zeroed-every-call region first
    unsigned long long* packed = (unsigned long long*)d_ws;   // N (8B aligned)
    float*  pooled   = (float*)(packed + N);                  // G*128
    float*  counts   = pooled + (size_t)G * D_OUT;            // G
    unsigned* csr    = (unsigned*)(counts + G);               // E + 8N (zeroed -> pads are 0)
    // ---- rest (not zeroed)
    int*    pos      = (int*)(csr + CSR_CAP);                 // E
    float*  dis      = (float*)(pos + E);                     // N
    unsigned char* h = (unsigned char*)(dis + N);             // N*128 fp8
    ushort* Wtg      = (ushort*)(h + (size_t)N * D_OUT);      // 32768 bf16
    int*    row_start= (int*)(Wtg + D_IN * D_OUT);            // N+1
    int*    blksum   = row_start + N + 1;                     // NB
    int*    blkpre   = blksum + NB;                           // NB

    size_t zbytes = (size_t)N * 8 + ((size_t)G * D_OUT + G) * sizeof(float)
                  + (size_t)CSR_CAP * sizeof(unsigned);
    hipMemsetAsync(packed, 0, zbytes, stream);

    wt_k      <<<(D_IN * D_OUT + 255) / 256, 256, 0, stream>>>(Wc, Wtg);

    fused_k   <<<EB + GB, 256, 32768, stream>>>(dst, ew, packed, pos, E, GB,
                                                x, Wtg, h, N);

    scan1_k   <<<NB, 256, 0, stream>>>(packed, row_start, blksum, dis, N);
    scan2_k   <<<1, 256, 0, stream>>>(blksum, blkpre, NB, row_start, N);

    fill_k    <<<(E + 255) / 256, 256, 0, stream>>>(src, dst, ew, pos, row_start, blkpre, dis, csr, E);

    agg_pool_k<<<(N + 63) / 64, 256, 0, stream>>>(row_start, blkpre, csr, h, dis, bc, batch,
                                                  pooled, counts, N);

    head_k    <<<G, 64, 0, stream>>>(pooled, counts, Wl, bl, out, G);
}